// Round 4
// baseline (57.973 us; speedup 1.0000x reference)
//
#include <hip/hip_runtime.h>
#include <math.h>

#define D 20
#define NROWS 1000000
#define NTILES (NROWS / 16)          // 62500 16-row tiles
#define TPB 256
#define NBLK 1024                    // 4/CU -> all-resident, no tail
#define WT (NBLK * (TPB / 64))       // 4096 waves

typedef float  f32x4  __attribute__((ext_vector_type(4)));
typedef __bf16 bf16x8 __attribute__((ext_vector_type(8)));

// ws layout: [0, NBLK*16) partial (S,Sabs) doubles; [NBLK*16, +4) atomic counter
// counter is zeroed by a hipMemsetAsync graph node every launch -> poison/replay safe.
#define CNT_OFF (NBLK * 16)

// ---------------------------------------------------------------------------
// Per-lane MFMA constant-fragment builders (16x16x32 bf16).
// B1 (GEMM1 A-operand): row m=mbase+ii, k=G*8+e indexes j of A[j][m]; k==20 -> c[m].
// B2 (GEMM2 B-operand): col n=nbase+ii, SIGMA-permuted k-rows
//   sigma(G,e) = e<4 ? 4G+e : 16+4G+(e-4); sigma==20 -> b[n]. The permutation is
//   chosen so GEMM1's accumulator regs feed GEMM2's A-fragment with NO cross-lane ops.
// ---------------------------------------------------------------------------
__device__ inline bf16x8 mk_frag_b1(const float* A_s, const float* c_s,
                                    int G, int ii, int mbase) {
  bf16x8 f;
#pragma unroll
  for (int e = 0; e < 8; ++e) {
    int k = G * 8 + e;
    int m = mbase + ii;
    float v = 0.f;
    if (m < D) v = (k < D) ? A_s[k * D + m] : (k == D ? c_s[m] : 0.f);
    f[e] = (__bf16)v;
  }
  return f;
}
__device__ inline bf16x8 mk_frag_b2(const float* __restrict__ W,
                                    const float* __restrict__ b,
                                    int G, int ii, int nbase) {
  bf16x8 f;
#pragma unroll
  for (int e = 0; e < 8; ++e) {
    int sg = (e < 4) ? (4 * G + e) : (16 + 4 * G + (e - 4));
    int n = nbase + ii;
    float v = 0.f;
    if (n < D) v = (sg < D) ? W[n * D + sg] : (sg == D ? b[n] : 0.f);
    f[e] = (__bf16)v;
  }
  return f;
}

// ---------------------------------------------------------------------------
// ONE fused kernel: per-block setup -> grid-stride MFMA loop (2-deep prefetch)
// -> per-block partial -> last-arriving block finalizes (fixed-order reduce =
// deterministic) and computes the exact halving count in scalar f64.
// ---------------------------------------------------------------------------
__global__ __launch_bounds__(TPB) void fused_kernel(
    const float* __restrict__ X, const float* __restrict__ W,
    const float* __restrict__ b, const float* __restrict__ R,
    double* __restrict__ partial, unsigned int* __restrict__ counter,
    float* __restrict__ out) {
  __shared__ float A_s[D * D];
  __shared__ float c_s[D];
  __shared__ double red[8];
  __shared__ int amLast;
  const int tid = threadIdx.x;

  // ---- per-block fold of the first two layers (A = W^T R, c = bR + 1) ----
  for (int t = tid; t < D * D + D; t += TPB) {
    if (t < D * D) {
      int j = t / D, m = t % D;
      float s = 0.f;
#pragma unroll
      for (int i = 0; i < D; ++i) s = fmaf(W[i * D + j], R[i * D + m], s);
      A_s[t] = s;
    } else {
      int m = t - D * D;
      float s = 1.0f;
#pragma unroll
      for (int i = 0; i < D; ++i) s = fmaf(b[i], R[i * D + m], s);
      c_s[m] = s;
    }
  }
  __syncthreads();

  const int lane = tid & 63;
  const int G = lane >> 4, ii = lane & 15;
  const int wid = tid >> 6;
  const bf16x8 B1t1 = mk_frag_b1(A_s, c_s, G, ii, 0);
  const bf16x8 B1t2 = mk_frag_b1(A_s, c_s, G, ii, 16);
  const bf16x8 B2t1 = mk_frag_b2(W, b, G, ii, 0);
  const bf16x8 B2t2 = mk_frag_b2(W, b, G, ii, 16);

  // ---- main loop: one 16-row tile per wave-iter, 2-deep prefetch ----
  const int gw = blockIdx.x * (TPB / 64) + wid;
  const int g8 = (G < 2) ? G * 8 : 16;                 // this lane's k-offset
  const float* lbase = X + (size_t)ii * D + g8;        // + tile*320 floats
  double s64 = 0.0, sa64 = 0.0;

#define PREF(tn, va, vb)                                          \
  do {                                                            \
    va = (float4){0.f, 0.f, 0.f, 0.f};                            \
    vb = (float4){0.f, 0.f, 0.f, 0.f};                            \
    if ((tn) < NTILES) {                                          \
      const float* p = lbase + (size_t)(tn) * (16 * D);           \
      if (G < 3) va = *(const float4*)p;                          \
      if (G < 2) vb = *(const float4*)(p + 4);                    \
    }                                                             \
  } while (0)

#define TILE_BODY(ca, cb, pf_tile, pa, pb)                                    \
  do {                                                                        \
    const float e4 = (G == 2) ? 1.0f : (cb).x; /* k=20 slot carries 1.0 */    \
    bf16x8 xf;                                                                \
    xf[0] = (__bf16)(ca).x; xf[1] = (__bf16)(ca).y;                           \
    xf[2] = (__bf16)(ca).z; xf[3] = (__bf16)(ca).w;                           \
    xf[4] = (__bf16)e4;     xf[5] = (__bf16)(cb).y;                           \
    xf[6] = (__bf16)(cb).z; xf[7] = (__bf16)(cb).w;                           \
    PREF(pf_tile, pa, pb); /* issue next loads before the MFMAs */            \
    const f32x4 zz = {0.f, 0.f, 0.f, 0.f};                                    \
    f32x4 a1 = __builtin_amdgcn_mfma_f32_16x16x32_bf16(B1t1, xf, zz, 0, 0, 0);\
    f32x4 a2 = __builtin_amdgcn_mfma_f32_16x16x32_bf16(B1t2, xf, zz, 0, 0, 0);\
    _Pragma("unroll")                                                         \
    for (int q = 0; q < 4; ++q) {                                             \
      a1[q] = fmaxf(a1[q], 0.f);                                              \
      a2[q] = fmaxf(a2[q], 0.f);                                              \
    }                                                                         \
    const float hj = (G == 1) ? 1.0f : a2[0]; /* m=20 slot = 1.0 (b-row) */   \
    bf16x8 x2f;                                                               \
    x2f[0] = (__bf16)a1[0]; x2f[1] = (__bf16)a1[1];                           \
    x2f[2] = (__bf16)a1[2]; x2f[3] = (__bf16)a1[3];                           \
    x2f[4] = (__bf16)hj;    x2f[5] = (__bf16)a2[1];                           \
    x2f[6] = (__bf16)a2[2]; x2f[7] = (__bf16)a2[3];                           \
    f32x4 z1 = __builtin_amdgcn_mfma_f32_16x16x32_bf16(x2f, B2t1, zz, 0, 0, 0);\
    f32x4 z2 = __builtin_amdgcn_mfma_f32_16x16x32_bf16(x2f, B2t2, zz, 0, 0, 0);\
    const float s8 = ((z1[0] + z1[1]) + (z1[2] + z1[3])) +                    \
                     ((z2[0] + z2[1]) + (z2[2] + z2[3]));                     \
    const float sa8 =                                                         \
        ((fabsf(z1[0]) + fabsf(z1[1])) + (fabsf(z1[2]) + fabsf(z1[3]))) +     \
        ((fabsf(z2[0]) + fabsf(z2[1])) + (fabsf(z2[2]) + fabsf(z2[3])));      \
    s64 += (double)s8;                                                        \
    sa64 += (double)sa8;                                                      \
  } while (0)

  float4 p0a, p0b, p1a, p1b;
  PREF(gw, p0a, p0b);
  PREF(gw + WT, p1a, p1b);
  for (int t = gw; t < NTILES; t += 2 * WT) {
    TILE_BODY(p0a, p0b, t + 2 * WT, p0a, p0b);
    if (t + WT < NTILES) {
      TILE_BODY(p1a, p1b, t + 3 * WT, p1a, p1b);
    }
  }

  // ---- block reduce: wave64 shfl (f64) -> 4-wave LDS -> one pair/block ----
#pragma unroll
  for (int off = 32; off > 0; off >>= 1) {
    s64 += __shfl_down(s64, off, 64);
    sa64 += __shfl_down(sa64, off, 64);
  }
  if ((tid & 63) == 0) { red[wid * 2] = s64; red[wid * 2 + 1] = sa64; }
  __syncthreads();
  if (tid == 0) {
    partial[2 * blockIdx.x]     = red[0] + red[2] + red[4] + red[6];
    partial[2 * blockIdx.x + 1] = red[1] + red[3] + red[5] + red[7];
    __threadfence();                       // release partials (device scope)
    unsigned int old = atomicAdd(counter, 1u);
    amLast = (old == NBLK - 1);
  }
  __syncthreads();

  // ---- last-arriving block: deterministic fixed-order final reduce ----
  if (amLast) {
    __threadfence();                       // acquire all partials
    double s = 0.0, sa = 0.0;
    for (int i = tid; i < NBLK; i += TPB) {
      s += partial[2 * i];
      sa += partial[2 * i + 1];
    }
#pragma unroll
    for (int off = 32; off > 0; off >>= 1) {
      s += __shfl_down(s, off, 64);
      sa += __shfl_down(sa, off, 64);
    }
    if ((tid & 63) == 0) { red[wid * 2] = s; red[wid * 2 + 1] = sa; }
    __syncthreads();
    if (tid == 0) {
      double S  = red[0] + red[2] + red[4] + red[6];
      double SA = red[1] + red[3] + red[5] + red[7];
      int k = 0;
      double tt = SA;
      while (tt > 1.0 && k < 4096) { tt *= 0.5; ++k; }  // exact: /2 per ref iter
      out[0] = (float)ldexp(S, -k);
    }
  }
}

extern "C" void kernel_launch(void* const* d_in, const int* in_sizes, int n_in,
                              void* d_out, int out_size, void* d_ws, size_t ws_size,
                              hipStream_t stream) {
  const float* X = (const float*)d_in[0];
  const float* W = (const float*)d_in[1];
  const float* b = (const float*)d_in[2];
  const float* R = (const float*)d_in[3];
  char* ws = (char*)d_ws;
  double* partial = (double*)ws;
  unsigned int* counter = (unsigned int*)(ws + CNT_OFF);

  hipMemsetAsync(counter, 0, sizeof(unsigned int), stream);  // capture-legal node
  fused_kernel<<<NBLK, TPB, 0, stream>>>(X, W, b, R, partial, counter,
                                         (float*)d_out);
}